// Round 1
// baseline (567.740 us; speedup 1.0000x reference)
//
#include <hip/hip_runtime.h>
#include <cstdint>
#include <cstddef>

#ifndef INFINITY
#define INFINITY (__builtin_inff())
#endif

// ---------------------------------------------------------------- reductions
__global__ void reduce_sum_kernel(const float* __restrict__ x, int n, float* __restrict__ out) {
    float s = 0.f;
    for (int i = blockIdx.x * blockDim.x + threadIdx.x; i < n; i += gridDim.x * blockDim.x)
        s += x[i];
    for (int o = 32; o; o >>= 1) s += __shfl_xor(s, o, 64);
    if ((threadIdx.x & 63) == 0) atomicAdd(out, s);
}

// ---------------------------------------------------------------- CSR build
__global__ void degree_kernel(const int* __restrict__ ei, int* __restrict__ deg, int E, int N) {
    int e = blockIdx.x * blockDim.x + threadIdx.x;
    if (e >= E + N) return;
    int d = (e < E) ? ei[E + e] : (e - E);
    atomicAdd(&deg[d], 1);
}

__global__ void scan_partial(const int* __restrict__ deg, int n, int* __restrict__ bsum) {
    __shared__ int lds[256];
    int t = threadIdx.x;
    int base = blockIdx.x * 1024 + t * 4;
    int s = 0;
#pragma unroll
    for (int j = 0; j < 4; ++j) if (base + j < n) s += deg[base + j];
    lds[t] = s; __syncthreads();
    for (int o = 128; o; o >>= 1) { if (t < o) lds[t] += lds[t + o]; __syncthreads(); }
    if (t == 0) bsum[blockIdx.x] = lds[0];
}

__global__ void scan_block(const int* __restrict__ bsum, int nb, int* __restrict__ boff,
                           int* __restrict__ row_start, int n, int total) {
    __shared__ int lds[256];
    int t = threadIdx.x;
    int v = (t < nb) ? bsum[t] : 0;
    lds[t] = v; __syncthreads();
    for (int o = 1; o < 256; o <<= 1) {
        int y = (t >= o) ? lds[t - o] : 0;
        __syncthreads();
        lds[t] += y;
        __syncthreads();
    }
    if (t < nb) boff[t] = lds[t] - v;   // exclusive
    if (t == 0) row_start[n] = total;
}

__global__ void scan_final(const int* __restrict__ deg, int n, const int* __restrict__ boff,
                           int* __restrict__ row_start) {
    __shared__ int lds[256];
    int t = threadIdx.x;
    int base = blockIdx.x * 1024 + t * 4;
    int d[4], loc[4], s = 0;
#pragma unroll
    for (int j = 0; j < 4; ++j) d[j] = (base + j < n) ? deg[base + j] : 0;
#pragma unroll
    for (int j = 0; j < 4; ++j) { loc[j] = s; s += d[j]; }
    lds[t] = s; __syncthreads();
    for (int o = 1; o < 256; o <<= 1) {
        int y = (t >= o) ? lds[t - o] : 0;
        __syncthreads();
        lds[t] += y;
        __syncthreads();
    }
    int texcl = lds[t] - s + boff[blockIdx.x];
#pragma unroll
    for (int j = 0; j < 4; ++j) if (base + j < n) row_start[base + j] = texcl + loc[j];
}

__global__ void scatter_kernel(const int* __restrict__ ei, const float* __restrict__ ew,
                               const float* __restrict__ ew_sum, const int* __restrict__ row_start,
                               int* __restrict__ cursor, int* __restrict__ csr_src,
                               float* __restrict__ csr_ea, int E, int N) {
    int e = blockIdx.x * blockDim.x + threadIdx.x;
    if (e >= E + N) return;
    int s, d; float w;
    if (e < E) { s = ei[e]; d = ei[E + e]; w = ew[e]; }
    else       { s = d = e - E;            w = ew_sum[0] / (float)E; }
    int pos = row_start[d] + atomicAdd(&cursor[d], 1);
    csr_src[pos] = s;
    csr_ea[pos] = w;
}

// ---------------------------------------------------------------- linear (X[n,128] @ W[128,M] + B)
template <int M>
__global__ __launch_bounds__(256) void linear_kernel(const float* __restrict__ X,
                                                     const float* __restrict__ W,
                                                     const float* __restrict__ B,
                                                     float* __restrict__ Y, int n) {
    constexpr int K = 128, KT = 32, ROWS = 64, MC = M / 32;
    __shared__ float sA[ROWS][KT];
    __shared__ float sW[KT][M];
    int t = threadIdx.x;
    int r0 = blockIdx.x * ROWS;
    int tc = t & 31, tr = t >> 5;
    float acc[8][MC];
#pragma unroll
    for (int i = 0; i < 8; ++i)
#pragma unroll
        for (int j = 0; j < MC; ++j) acc[i][j] = 0.f;

    for (int k0 = 0; k0 < K; k0 += KT) {
#pragma unroll
        for (int i = 0; i < 2; ++i) {              // A tile: 512 float4
            int f = t + i * 256;
            int row = f >> 3, q = f & 7;
            float4 v = make_float4(0.f, 0.f, 0.f, 0.f);
            if (r0 + row < n) v = *(const float4*)&X[(size_t)(r0 + row) * K + k0 + q * 4];
            *(float4*)&sA[row][q * 4] = v;
        }
        constexpr int WF4 = KT * M / 4 / 256;      // W tile: contiguous
#pragma unroll
        for (int i = 0; i < WF4; ++i) {
            int f = t + i * 256;
            *(float4*)&sW[0][f * 4] = *(const float4*)&W[(size_t)k0 * M + f * 4];
        }
        __syncthreads();
#pragma unroll
        for (int kk = 0; kk < KT; ++kk) {
            float a[8];
#pragma unroll
            for (int i = 0; i < 8; ++i) a[i] = sA[tr * 8 + i][kk];
            float w[MC];
#pragma unroll
            for (int j = 0; j < MC; ++j) w[j] = sW[kk][tc + 32 * j];
#pragma unroll
            for (int i = 0; i < 8; ++i)
#pragma unroll
                for (int j = 0; j < MC; ++j) acc[i][j] = fmaf(a[i], w[j], acc[i][j]);
        }
        __syncthreads();
    }
#pragma unroll
    for (int i = 0; i < 8; ++i) {
        int row = r0 + tr * 8 + i;
        if (row < n) {
#pragma unroll
            for (int j = 0; j < MC; ++j)
                Y[(size_t)row * M + tc + 32 * j] = acc[i][j] + B[tc + 32 * j];
        }
    }
}

// ---------------------------------------------------------------- GATv2 aggregation: one wave per dst node
template <int H, int C>
__global__ __launch_bounds__(256) void gat_agg(const float* __restrict__ xl, const float* __restrict__ xr,
                                               const int* __restrict__ row_start,
                                               const int* __restrict__ csr_src,
                                               const float* __restrict__ csr_ea,
                                               const float* __restrict__ We, const float* __restrict__ att,
                                               const float* __restrict__ bias,
                                               float* __restrict__ out, int n) {
    constexpr int HC = H * C;
    constexpr int VPL = HC / 64;   // values per lane
    constexpr int RW = 64 / H;     // softmax reduce width (lanes per head)
    int wid = threadIdx.x >> 6;
    int lane = threadIdx.x & 63;
    int v = blockIdx.x * (blockDim.x >> 6) + wid;
    if (v >= n) return;

    int base = lane * VPL;
    float xrv[VPL], wE[VPL], attv[VPL];
#pragma unroll
    for (int j = 0; j < VPL; ++j) {
        xrv[j] = xr[(size_t)v * HC + base + j];
        wE[j] = We[base + j];
        attv[j] = att[base + j];
    }

    float m = -INFINITY, den = 0.f;
    float acc[VPL];
#pragma unroll
    for (int j = 0; j < VPL; ++j) acc[j] = 0.f;

    int e0 = row_start[v], e1 = row_start[v + 1];
    for (int e = e0; e < e1; ++e) {
        int s = csr_src[e];
        float w = csr_ea[e];
        float xls[VPL];
        if constexpr (VPL == 2) {
            float2 t2 = *(const float2*)&xl[(size_t)s * HC + base];
            xls[0] = t2.x; xls[1] = t2.y;
        } else {
            float4 t4 = *(const float4*)&xl[(size_t)s * HC + base];
            xls[0] = t4.x; xls[1] = t4.y; xls[2] = t4.z; xls[3] = t4.w;
        }
        float p = 0.f;
#pragma unroll
        for (int j = 0; j < VPL; ++j) {
            float mm = xls[j] + xrv[j] + w * wE[j];
            mm = mm > 0.f ? mm : 0.2f * mm;
            p += mm * attv[j];
        }
#pragma unroll
        for (int o = RW >> 1; o; o >>= 1) p += __shfl_xor(p, o, 64);
        // online softmax update
        float mn = fmaxf(m, p);
        float sc = __expf(m - mn);
        float pe = __expf(p - mn);
        den = den * sc + pe;
#pragma unroll
        for (int j = 0; j < VPL; ++j) acc[j] = acc[j] * sc + pe * xls[j];
        m = mn;
    }

    float inv = 1.f / (den + 1e-16f);
#pragma unroll
    for (int j = 0; j < VPL; ++j) acc[j] *= inv;
    // mean over heads: reduce lanes offset by multiples of RW
#pragma unroll
    for (int o = RW; o < 64; o <<= 1)
#pragma unroll
        for (int j = 0; j < VPL; ++j) acc[j] += __shfl_xor(acc[j], o, 64);

    if (lane < RW) {
#pragma unroll
        for (int j = 0; j < VPL; ++j)
            out[(size_t)v * C + base + j] = acc[j] * (1.f / (float)H) + bias[base + j];
    }
}

// ---------------------------------------------------------------- batchnorm
__global__ void bn_stats(const float* __restrict__ x, int n, int C, float* __restrict__ sums) {
    int t = threadIdx.x;
    int col = t & (C - 1);
    int rpb = 256 / C;
    int row = blockIdx.x * rpb + t / C;
    float s = 0.f, sq = 0.f;
    for (; row < n; row += gridDim.x * rpb) {
        float v = x[(size_t)row * C + col];
        s += v; sq += v * v;
    }
    atomicAdd(&sums[col], s);
    atomicAdd(&sums[C + col], sq);
}

__global__ void bn_apply_elu(float* __restrict__ x, int n, int C,
                             const float* __restrict__ g, const float* __restrict__ be,
                             const float* __restrict__ sums) {
    int total = n * C / 4;
    float invn = 1.f / (float)n;
    for (int i = blockIdx.x * blockDim.x + threadIdx.x; i < total; i += gridDim.x * blockDim.x) {
        float4 v = ((float4*)x)[i];
        int c0 = (i * 4) & (C - 1);
        float r[4] = {v.x, v.y, v.z, v.w};
#pragma unroll
        for (int j = 0; j < 4; ++j) {
            int c = c0 + j;
            float mu = sums[c] * invn;
            float var = sums[C + c] * invn - mu * mu;
            float t = g[c] * (r[j] - mu) * rsqrtf(var + 1e-5f) + be[c];
            r[j] = t > 0.f ? t : expm1f(t);
        }
        ((float4*)x)[i] = make_float4(r[0], r[1], r[2], r[3]);
    }
}

// ---------------------------------------------------------------- launch
extern "C" void kernel_launch(void* const* d_in, const int* in_sizes, int n_in,
                              void* d_out, int out_size, void* d_ws, size_t ws_size,
                              hipStream_t stream) {
    const float* emb = (const float*)d_in[0];
    const float* ew  = (const float*)d_in[1];
    const float* Wl0 = (const float*)d_in[2];
    const float* bl0 = (const float*)d_in[3];
    const float* Wr0 = (const float*)d_in[4];
    const float* br0 = (const float*)d_in[5];
    const float* We0 = (const float*)d_in[6];
    const float* att0 = (const float*)d_in[7];
    const float* b0  = (const float*)d_in[8];
    const float* g0  = (const float*)d_in[9];
    const float* be0 = (const float*)d_in[10];
    const float* Wl1 = (const float*)d_in[11];
    const float* bl1 = (const float*)d_in[12];
    const float* Wr1 = (const float*)d_in[13];
    const float* br1 = (const float*)d_in[14];
    const float* We1 = (const float*)d_in[15];
    const float* att1 = (const float*)d_in[16];
    const float* b1  = (const float*)d_in[17];
    const float* g1  = (const float*)d_in[18];
    const float* be1 = (const float*)d_in[19];
    const int* ei    = (const int*)d_in[20];

    const int N = in_sizes[0] / 128;
    const int E = in_sizes[1];
    const int Et = E + N;
    float* out = (float*)d_out;

    // workspace carve-up (256B aligned)
    char* w = (char*)d_ws;
    size_t off = 0;
    auto alloc = [&](size_t bytes) {
        void* p = w + off;
        off = (off + bytes + 255) & ~(size_t)255;
        return p;
    };
    float* xlbuf   = (float*)alloc((size_t)N * 256 * 4);  // xl0 (N*128) then xl1 (N*256)
    float* xrbuf   = (float*)alloc((size_t)N * 256 * 4);  // xr0 then xr1
    float* h0      = (float*)alloc((size_t)N * 128 * 4);
    int*   deg     = (int*)alloc((size_t)N * 4);
    int*   row_st  = (int*)alloc((size_t)(N + 1) * 4);
    int*   cursor  = (int*)alloc((size_t)N * 4);
    int*   csr_src = (int*)alloc((size_t)Et * 4);
    float* csr_ea  = (float*)alloc((size_t)Et * 4);
    int*   bsum    = (int*)alloc(256 * 4);
    int*   boff    = (int*)alloc(256 * 4);
    float* ew_sum  = (float*)alloc(256);
    float* bn0     = (float*)alloc(256 * 4);
    float* bn1     = (float*)alloc(128 * 4);
    (void)ws_size; (void)n_in; (void)out_size;

    hipMemsetAsync(deg, 0, (size_t)N * 4, stream);
    hipMemsetAsync(cursor, 0, (size_t)N * 4, stream);
    hipMemsetAsync(ew_sum, 0, 4, stream);
    hipMemsetAsync(bn0, 0, 256 * 4, stream);
    hipMemsetAsync(bn1, 0, 128 * 4, stream);

    // edge-weight mean + CSR by dst
    reduce_sum_kernel<<<256, 256, 0, stream>>>(ew, E, ew_sum);
    degree_kernel<<<(Et + 255) / 256, 256, 0, stream>>>(ei, deg, E, N);
    const int NB1 = (N + 1023) / 1024;
    scan_partial<<<NB1, 256, 0, stream>>>(deg, N, bsum);
    scan_block<<<1, 256, 0, stream>>>(bsum, NB1, boff, row_st, N, Et);
    scan_final<<<NB1, 256, 0, stream>>>(deg, N, boff, row_st);
    scatter_kernel<<<(Et + 255) / 256, 256, 0, stream>>>(ei, ew, ew_sum, row_st, cursor,
                                                         csr_src, csr_ea, E, N);

    // ---- layer 0
    const int GB = (N + 63) / 64;
    linear_kernel<128><<<GB, 256, 0, stream>>>(emb, Wl0, bl0, xlbuf, N);
    linear_kernel<128><<<GB, 256, 0, stream>>>(emb, Wr0, br0, xrbuf, N);
    gat_agg<1, 128><<<(N + 3) / 4, 256, 0, stream>>>(xlbuf, xrbuf, row_st, csr_src, csr_ea,
                                                     We0, att0, b0, h0, N);
    bn_stats<<<512, 256, 0, stream>>>(h0, N, 128, bn0);
    bn_apply_elu<<<2048, 256, 0, stream>>>(h0, N, 128, g0, be0, bn0);

    // ---- layer 1
    linear_kernel<256><<<GB, 256, 0, stream>>>(h0, Wl1, bl1, xlbuf, N);
    linear_kernel<256><<<GB, 256, 0, stream>>>(h0, Wr1, br1, xrbuf, N);
    gat_agg<4, 64><<<(N + 3) / 4, 256, 0, stream>>>(xlbuf, xrbuf, row_st, csr_src, csr_ea,
                                                    We1, att1, b1, out, N);
    bn_stats<<<512, 256, 0, stream>>>(out, N, 64, bn1);
    bn_apply_elu<<<2048, 256, 0, stream>>>(out, N, 64, g1, be1, bn1);
}

// Round 2
// 441.925 us; speedup vs baseline: 1.2847x; 1.2847x over previous
//
#include <hip/hip_runtime.h>
#include <cstdint>
#include <cstddef>

using f32x4 = __attribute__((ext_vector_type(4))) float;
using s16x8 = __attribute__((ext_vector_type(8))) short;

__device__ __forceinline__ ushort f2bf(float x) {
    uint32_t u = __builtin_bit_cast(uint32_t, x);
    u += 0x7fffu + ((u >> 16) & 1u);          // round-to-nearest-even
    return (ushort)(u >> 16);
}
__device__ __forceinline__ float bflo(uint32_t u) { return __builtin_bit_cast(float, u << 16); }
__device__ __forceinline__ float bfhi(uint32_t u) { return __builtin_bit_cast(float, u & 0xffff0000u); }

// ---------------------------------------------------------------- reductions
__global__ void reduce_sum_kernel(const float* __restrict__ x, int n, float* __restrict__ out) {
    float s = 0.f;
    for (int i = blockIdx.x * blockDim.x + threadIdx.x; i < n; i += gridDim.x * blockDim.x)
        s += x[i];
    for (int o = 32; o; o >>= 1) s += __shfl_xor(s, o, 64);
    if ((threadIdx.x & 63) == 0) atomicAdd(out, s);
}

// ---------------------------------------------------------------- CSR build
__global__ void degree_kernel(const int* __restrict__ ei, int* __restrict__ deg, int E, int N) {
    int e = blockIdx.x * blockDim.x + threadIdx.x;
    if (e >= E + N) return;
    int d = (e < E) ? ei[E + e] : (e - E);
    atomicAdd(&deg[d], 1);
}

__global__ void scan_partial(const int* __restrict__ deg, int n, int* __restrict__ bsum) {
    __shared__ int lds[256];
    int t = threadIdx.x;
    int base = blockIdx.x * 1024 + t * 4;
    int s = 0;
#pragma unroll
    for (int j = 0; j < 4; ++j) if (base + j < n) s += deg[base + j];
    lds[t] = s; __syncthreads();
    for (int o = 128; o; o >>= 1) { if (t < o) lds[t] += lds[t + o]; __syncthreads(); }
    if (t == 0) bsum[blockIdx.x] = lds[0];
}

__global__ void scan_block(const int* __restrict__ bsum, int nb, int* __restrict__ boff,
                           int* __restrict__ row_start, int n, int total) {
    __shared__ int lds[256];
    int t = threadIdx.x;
    int v = (t < nb) ? bsum[t] : 0;
    lds[t] = v; __syncthreads();
    for (int o = 1; o < 256; o <<= 1) {
        int y = (t >= o) ? lds[t - o] : 0;
        __syncthreads();
        lds[t] += y;
        __syncthreads();
    }
    if (t < nb) boff[t] = lds[t] - v;   // exclusive
    if (t == 0) row_start[n] = total;
}

__global__ void scan_final(const int* __restrict__ deg, int n, const int* __restrict__ boff,
                           int* __restrict__ row_start) {
    __shared__ int lds[256];
    int t = threadIdx.x;
    int base = blockIdx.x * 1024 + t * 4;
    int d[4], loc[4], s = 0;
#pragma unroll
    for (int j = 0; j < 4; ++j) d[j] = (base + j < n) ? deg[base + j] : 0;
#pragma unroll
    for (int j = 0; j < 4; ++j) { loc[j] = s; s += d[j]; }
    lds[t] = s; __syncthreads();
    for (int o = 1; o < 256; o <<= 1) {
        int y = (t >= o) ? lds[t - o] : 0;
        __syncthreads();
        lds[t] += y;
        __syncthreads();
    }
    int texcl = lds[t] - s + boff[blockIdx.x];
#pragma unroll
    for (int j = 0; j < 4; ++j) if (base + j < n) row_start[base + j] = texcl + loc[j];
}

__global__ void scatter_kernel(const int* __restrict__ ei, const float* __restrict__ ew,
                               const float* __restrict__ ew_sum, const int* __restrict__ row_start,
                               int* __restrict__ cursor, int* __restrict__ csr_src,
                               float* __restrict__ csr_ea, int E, int N) {
    int e = blockIdx.x * blockDim.x + threadIdx.x;
    if (e >= E + N) return;
    int s, d; float w;
    if (e < E) { s = ei[e]; d = ei[E + e]; w = ew[e]; }
    else       { s = d = e - E;            w = ew_sum[0] / (float)E; }
    int pos = row_start[d] + atomicAdd(&cursor[d], 1);
    csr_src[pos] = s;
    csr_ea[pos] = w;
}

// ---------------------------------------------------------------- conversions
__global__ void f32_to_bf16_kernel(const float* __restrict__ in, ushort* __restrict__ out, int n4) {
    for (int i = blockIdx.x * blockDim.x + threadIdx.x; i < n4; i += gridDim.x * blockDim.x) {
        float4 v = ((const float4*)in)[i];
        ushort4 o;
        o.x = f2bf(v.x); o.y = f2bf(v.y); o.z = f2bf(v.z); o.w = f2bf(v.w);
        ((ushort4*)out)[i] = o;
    }
}

// W [128][HALF] (x2) -> WT bf16 [2*HALF][128]
__global__ void wt_build(const float* __restrict__ Wl, const float* __restrict__ Wr,
                         ushort* __restrict__ WT, int HALF) {
    int MT = 2 * HALF;
    int idx = blockIdx.x * 256 + threadIdx.x;
    if (idx >= 128 * MT) return;
    int k = idx / MT, c = idx % MT;
    float v = (c < HALF) ? Wl[k * HALF + c] : Wr[k * HALF + (c - HALF)];
    WT[(size_t)c * 128 + k] = f2bf(v);
}

// ---------------------------------------------------------------- fused MFMA linear
// Y[:, :MT] = X[n,128] @ [Wl|Wr] + [bl|br], written as bf16 into xl / xr halves.
// A,B fragments use a consistent contiguous k-map (one ds_read_b128 each);
// result invariant under k-permutation since A/B layouts mirror each other.
template <int MT>
__global__ __launch_bounds__(256) void mfma_linear(const ushort* __restrict__ Xb,
                                                   const ushort* __restrict__ WT,
                                                   const float* __restrict__ bl,
                                                   const float* __restrict__ br,
                                                   ushort* __restrict__ xl,
                                                   ushort* __restrict__ xr, int n) {
    constexpr int HALF = MT / 2;
    constexpr int LDK = 136;                  // 272B row stride, 16B-aligned, bank-spread
    __shared__ __align__(16) ushort sA[128 * LDK];
    __shared__ __align__(16) ushort sB[128 * LDK];
    int t = threadIdx.x;
    int r0 = blockIdx.x * 128;
    int c0 = blockIdx.y * 128;

#pragma unroll
    for (int i = 0; i < 8; ++i) {             // stage A: 128 rows x 128 bf16
        int f = t + i * 256;
        int row = f >> 4, ch = f & 15;
        s16x8 v = {};
        if (r0 + row < n) v = *(const s16x8*)&Xb[(size_t)(r0 + row) * 128 + ch * 8];
        *(s16x8*)&sA[row * LDK + ch * 8] = v;
    }
#pragma unroll
    for (int i = 0; i < 8; ++i) {             // stage B: WT rows c0..c0+127
        int f = t + i * 256;
        int row = f >> 4, ch = f & 15;
        *(s16x8*)&sB[row * LDK + ch * 8] = *(const s16x8*)&WT[(size_t)(c0 + row) * 128 + ch * 8];
    }
    __syncthreads();

    int wid = t >> 6, l = t & 63;
    int lr = l & 15, lg = l >> 4;
    f32x4 acc[2][8] = {};
#pragma unroll
    for (int kk = 0; kk < 4; ++kk) {
        int ko = kk * 32 + lg * 8;
        s16x8 a0 = *(s16x8*)&sA[(wid * 32 + lr) * LDK + ko];
        s16x8 a1 = *(s16x8*)&sA[(wid * 32 + 16 + lr) * LDK + ko];
#pragma unroll
        for (int tn = 0; tn < 8; ++tn) {
            s16x8 b = *(s16x8*)&sB[(tn * 16 + lr) * LDK + ko];
            acc[0][tn] = __builtin_amdgcn_mfma_f32_16x16x32_bf16(a0, b, acc[0][tn], 0, 0, 0);
            acc[1][tn] = __builtin_amdgcn_mfma_f32_16x16x32_bf16(a1, b, acc[1][tn], 0, 0, 0);
        }
    }

    bool left = c0 < HALF;                    // whole block is one output half
    const float* bias = left ? bl : br;
    ushort* dst = left ? xl : xr;
    int cb = left ? c0 : c0 - HALF;
#pragma unroll
    for (int tn = 0; tn < 8; ++tn) {
        int colh = cb + tn * 16 + lr;
        float bv = bias[colh];
#pragma unroll
        for (int tm = 0; tm < 2; ++tm)
#pragma unroll
            for (int r = 0; r < 4; ++r) {
                int row = r0 + wid * 32 + tm * 16 + lg * 4 + r;
                if (row < n) dst[(size_t)row * HALF + colh] = f2bf(acc[tm][tn][r] + bv);
            }
    }
}

// ---------------------------------------------------------------- GATv2 aggregation (bf16 gathers)
template <int H, int C>
__global__ __launch_bounds__(256) void gat_agg(const ushort* __restrict__ xl, const ushort* __restrict__ xr,
                                               const int* __restrict__ row_start,
                                               const int* __restrict__ csr_src,
                                               const float* __restrict__ csr_ea,
                                               const float* __restrict__ We, const float* __restrict__ att,
                                               const float* __restrict__ bias,
                                               float* __restrict__ out, int n) {
    constexpr int HC = H * C;
    constexpr int VPL = HC / 64;   // values per lane (2 or 4)
    constexpr int RW = 64 / H;     // lanes per head
    int wid = threadIdx.x >> 6;
    int lane = threadIdx.x & 63;
    int v = blockIdx.x * (blockDim.x >> 6) + wid;
    if (v >= n) return;

    int base = lane * VPL;
    float xrv[VPL], wE[VPL], attv[VPL];
    if constexpr (VPL == 2) {
        uint32_t u = *(const uint32_t*)&xr[(size_t)v * HC + base];
        xrv[0] = bflo(u); xrv[1] = bfhi(u);
    } else {
        uint2 u = *(const uint2*)&xr[(size_t)v * HC + base];
        xrv[0] = bflo(u.x); xrv[1] = bfhi(u.x); xrv[2] = bflo(u.y); xrv[3] = bfhi(u.y);
    }
#pragma unroll
    for (int j = 0; j < VPL; ++j) { wE[j] = We[base + j]; attv[j] = att[base + j]; }

    float m0 = -__builtin_inff(), den0 = 0.f, a0[VPL];
    float m1 = -__builtin_inff(), den1 = 0.f, a1[VPL];
#pragma unroll
    for (int j = 0; j < VPL; ++j) { a0[j] = 0.f; a1[j] = 0.f; }

    auto step = [&](int e, float& m, float& den, float* acc) {
        int s = csr_src[e];
        float w = csr_ea[e];
        float xls[VPL];
        if constexpr (VPL == 2) {
            uint32_t u = *(const uint32_t*)&xl[(size_t)s * HC + base];
            xls[0] = bflo(u); xls[1] = bfhi(u);
        } else {
            uint2 u = *(const uint2*)&xl[(size_t)s * HC + base];
            xls[0] = bflo(u.x); xls[1] = bfhi(u.x); xls[2] = bflo(u.y); xls[3] = bfhi(u.y);
        }
        float p = 0.f;
#pragma unroll
        for (int j = 0; j < VPL; ++j) {
            float mm = xls[j] + xrv[j] + w * wE[j];
            mm = mm > 0.f ? mm : 0.2f * mm;
            p = fmaf(mm, attv[j], p);
        }
#pragma unroll
        for (int o = RW >> 1; o; o >>= 1) p += __shfl_xor(p, o, 64);
        float d = p - m;
        bool up = d > 0.f;
        float tt = __expf(up ? -d : d);   // exp(-|d|); first edge: exp(-inf)=0
        float sc = up ? tt : 1.f;
        float pe = up ? 1.f : tt;
        m = up ? p : m;
        den = fmaf(den, sc, pe);
#pragma unroll
        for (int j = 0; j < VPL; ++j) acc[j] = fmaf(acc[j], sc, pe * xls[j]);
    };

    int e0 = row_start[v], e1 = row_start[v + 1];
    int e = e0;
    for (; e + 2 <= e1; e += 2) { step(e, m0, den0, a0); step(e + 1, m1, den1, a1); }
    if (e < e1) step(e, m0, den0, a0);

    float mn = fmaxf(m0, m1);
    float s0 = __expf(m0 - mn), s1 = __expf(m1 - mn);
    float den = den0 * s0 + den1 * s1;
    float inv = 1.f / (den + 1e-16f);
    float acc[VPL];
#pragma unroll
    for (int j = 0; j < VPL; ++j) acc[j] = (a0[j] * s0 + a1[j] * s1) * inv;

    // mean over heads
#pragma unroll
    for (int o = RW; o < 64; o <<= 1)
#pragma unroll
        for (int j = 0; j < VPL; ++j) acc[j] += __shfl_xor(acc[j], o, 64);

    if (lane < RW) {
#pragma unroll
        for (int j = 0; j < VPL; ++j)
            out[(size_t)v * C + base + j] = acc[j] * (1.f / (float)H) + bias[base + j];
    }
}

// ---------------------------------------------------------------- batchnorm
__global__ void bn_stats(const float* __restrict__ x, int n, int C, float* __restrict__ sums) {
    int t = threadIdx.x;
    int col = t & (C - 1);
    int rpb = 256 / C;
    int row = blockIdx.x * rpb + t / C;
    float s = 0.f, sq = 0.f;
    for (; row < n; row += gridDim.x * rpb) {
        float v = x[(size_t)row * C + col];
        s += v; sq += v * v;
    }
    atomicAdd(&sums[col], s);
    atomicAdd(&sums[C + col], sq);
}

template <bool BF16OUT>
__global__ void bn_apply_elu(const float* __restrict__ x, int n, int C,
                             const float* __restrict__ g, const float* __restrict__ be,
                             const float* __restrict__ sums,
                             float* __restrict__ outf, ushort* __restrict__ outb) {
    int total = n * C / 4;
    float invn = 1.f / (float)n;
    for (int i = blockIdx.x * blockDim.x + threadIdx.x; i < total; i += gridDim.x * blockDim.x) {
        float4 v = ((const float4*)x)[i];
        int c0 = (i * 4) & (C - 1);
        float r[4] = {v.x, v.y, v.z, v.w};
#pragma unroll
        for (int j = 0; j < 4; ++j) {
            int c = c0 + j;
            float mu = sums[c] * invn;
            float var = sums[C + c] * invn - mu * mu;
            float t = g[c] * (r[j] - mu) * rsqrtf(var + 1e-5f) + be[c];
            r[j] = t > 0.f ? t : expm1f(t);
        }
        if constexpr (BF16OUT) {
            ushort4 o;
            o.x = f2bf(r[0]); o.y = f2bf(r[1]); o.z = f2bf(r[2]); o.w = f2bf(r[3]);
            ((ushort4*)outb)[i] = o;
        } else {
            ((float4*)outf)[i] = make_float4(r[0], r[1], r[2], r[3]);
        }
    }
}

// ---------------------------------------------------------------- launch
extern "C" void kernel_launch(void* const* d_in, const int* in_sizes, int n_in,
                              void* d_out, int out_size, void* d_ws, size_t ws_size,
                              hipStream_t stream) {
    const float* emb = (const float*)d_in[0];
    const float* ew  = (const float*)d_in[1];
    const float* Wl0 = (const float*)d_in[2];
    const float* bl0 = (const float*)d_in[3];
    const float* Wr0 = (const float*)d_in[4];
    const float* br0 = (const float*)d_in[5];
    const float* We0 = (const float*)d_in[6];
    const float* att0 = (const float*)d_in[7];
    const float* b0  = (const float*)d_in[8];
    const float* g0  = (const float*)d_in[9];
    const float* be0 = (const float*)d_in[10];
    const float* Wl1 = (const float*)d_in[11];
    const float* bl1 = (const float*)d_in[12];
    const float* Wr1 = (const float*)d_in[13];
    const float* br1 = (const float*)d_in[14];
    const float* We1 = (const float*)d_in[15];
    const float* att1 = (const float*)d_in[16];
    const float* b1  = (const float*)d_in[17];
    const float* g1  = (const float*)d_in[18];
    const float* be1 = (const float*)d_in[19];
    const int* ei    = (const int*)d_in[20];

    const int N = in_sizes[0] / 128;
    const int E = in_sizes[1];
    const int Et = E + N;
    float* out = (float*)d_out;

    char* w = (char*)d_ws;
    size_t off = 0;
    auto alloc = [&](size_t bytes) {
        void* p = w + off;
        off = (off + bytes + 255) & ~(size_t)255;
        return p;
    };
    ushort* xlb    = (ushort*)alloc((size_t)N * 256 * 2);
    ushort* xrb    = (ushort*)alloc((size_t)N * 256 * 2);
    float*  h0     = (float*)alloc((size_t)N * 128 * 4);
    ushort* h0b    = (ushort*)alloc((size_t)N * 128 * 2);
    ushort* embb   = (ushort*)alloc((size_t)N * 128 * 2);
    ushort* WT0    = (ushort*)alloc((size_t)256 * 128 * 2);
    ushort* WT1    = (ushort*)alloc((size_t)512 * 128 * 2);
    int*   deg     = (int*)alloc((size_t)N * 4);
    int*   row_st  = (int*)alloc((size_t)(N + 1) * 4);
    int*   cursor  = (int*)alloc((size_t)N * 4);
    int*   csr_src = (int*)alloc((size_t)Et * 4);
    float* csr_ea  = (float*)alloc((size_t)Et * 4);
    int*   bsum    = (int*)alloc(256 * 4);
    int*   boff    = (int*)alloc(256 * 4);
    float* ew_sum  = (float*)alloc(256);
    float* bn0     = (float*)alloc(256 * 4);
    float* bn1     = (float*)alloc(128 * 4);
    (void)ws_size; (void)n_in; (void)out_size;

    hipMemsetAsync(deg, 0, (size_t)N * 4, stream);
    hipMemsetAsync(cursor, 0, (size_t)N * 4, stream);
    hipMemsetAsync(ew_sum, 0, 4, stream);
    hipMemsetAsync(bn0, 0, 256 * 4, stream);
    hipMemsetAsync(bn1, 0, 128 * 4, stream);

    // CSR + conversions
    reduce_sum_kernel<<<256, 256, 0, stream>>>(ew, E, ew_sum);
    degree_kernel<<<(Et + 255) / 256, 256, 0, stream>>>(ei, deg, E, N);
    const int NB1 = (N + 1023) / 1024;
    scan_partial<<<NB1, 256, 0, stream>>>(deg, N, bsum);
    scan_block<<<1, 256, 0, stream>>>(bsum, NB1, boff, row_st, N, Et);
    scan_final<<<NB1, 256, 0, stream>>>(deg, N, boff, row_st);
    scatter_kernel<<<(Et + 255) / 256, 256, 0, stream>>>(ei, ew, ew_sum, row_st, cursor,
                                                         csr_src, csr_ea, E, N);
    f32_to_bf16_kernel<<<2048, 256, 0, stream>>>(emb, embb, N * 128 / 4);
    wt_build<<<(128 * 256 + 255) / 256, 256, 0, stream>>>(Wl0, Wr0, WT0, 128);
    wt_build<<<(128 * 512 + 255) / 256, 256, 0, stream>>>(Wl1, Wr1, WT1, 256);

    const int GBM = (N + 127) / 128;
    // ---- layer 0
    mfma_linear<256><<<dim3(GBM, 2), 256, 0, stream>>>(embb, WT0, bl0, br0, xlb, xrb, N);
    gat_agg<1, 128><<<(N + 3) / 4, 256, 0, stream>>>(xlb, xrb, row_st, csr_src, csr_ea,
                                                     We0, att0, b0, h0, N);
    bn_stats<<<512, 256, 0, stream>>>(h0, N, 128, bn0);
    bn_apply_elu<true><<<2048, 256, 0, stream>>>(h0, N, 128, g0, be0, bn0, nullptr, h0b);

    // ---- layer 1
    mfma_linear<512><<<dim3(GBM, 4), 256, 0, stream>>>(h0b, WT1, bl1, br1, xlb, xrb, N);
    gat_agg<4, 64><<<(N + 3) / 4, 256, 0, stream>>>(xlb, xrb, row_st, csr_src, csr_ea,
                                                    We1, att1, b1, out, N);
    bn_stats<<<512, 256, 0, stream>>>(out, N, 64, bn1);
    bn_apply_elu<false><<<2048, 256, 0, stream>>>(out, N, 64, g1, be1, bn1, out, nullptr);
}